// Round 13
// baseline (2247.137 us; speedup 1.0000x reference)
//
#include <hip/hip_runtime.h>
#include <hip/hip_bf16.h>
#include <stdint.h>

typedef __attribute__((ext_vector_type(4))) float    f32x4;
typedef __attribute__((ext_vector_type(8))) short    bf16x8;
typedef __attribute__((ext_vector_type(4))) uint32_t u32x4;
typedef unsigned short u16;

#define T_   256
#define B_   64
#define E_   1024
#define H_   1024
#define CLS  32000
#define NWG  256

// workspace layout (bytes)
#define OFF_XBF   0ull            // [16384][1024] bf16       33,554,432 (LIVE through k_lstm)
#define OFF_WHP   33554432ull     // [256 wg][Wi 64KB | Wh 64KB] 33,554,432
#define OFF_FLG   67108864ull     // [2*128] flags, 128B apart    32,768
#define OFF_BSUM  67141632ull     // [2][4096] f32                32,768
#define OFF_OBUF  67174400ull     // [2 dir][64][1024] f32       524,288
#define OFF_OSUM  67698688ull     // [64][1024] bf16             131,072
#define OFF_HROT  67829760ull     // rotating h: slot (s,dir) = (s*2+dir)*131072 B; 67,371,008

__device__ __forceinline__ u16 f2bf(float f) {
    union { float f; uint32_t i; } v; v.f = f;
    uint32_t r = v.i + 0x7fffu + ((v.i >> 16) & 1u);
    return (u16)(r >> 16);
}
__device__ __forceinline__ float sigm(float x)   { return 1.f / (1.f + __expf(-x)); }
__device__ __forceinline__ float tanh_f(float x) { return 1.f - 2.f / (__expf(2.f * x) + 1.f); }

// agent-coherent (MALL) accesses — bypass L1/L2, no cache-wide ops anywhere
__device__ __forceinline__ void ldg4_cc(unsigned& d, const unsigned* p) {
    asm volatile("global_load_dword %0, %1, off sc0 sc1"
                 : "=v"(d) : "v"(p) : "memory");
}
__device__ __forceinline__ void stg16_cc(u16* p, bf16x8 v) {
    asm volatile("global_store_dwordx4 %0, %1, off sc0 sc1"
                 :: "v"(p), "v"(v) : "memory");
}
__device__ __forceinline__ void stg4_cc(unsigned* p, unsigned v) {
    asm volatile("global_store_dword %0, %1, off sc0 sc1"
                 :: "v"(p), "v"(v) : "memory");
}
__device__ __forceinline__ void wait_vm0() {
    asm volatile("s_waitcnt vmcnt(0)" ::: "memory");
}

// ---------------- prep kernels ----------------

__global__ void k_gather(const int* __restrict__ X, const float* __restrict__ emb,
                         u16* __restrict__ xbf) {
    const int m = blockIdx.x;            // t*64+b
    const int t = m >> 6, b = m & 63;
    const int tok = X[b * T_ + t];
    const float* src = emb + (size_t)tok * E_;
    u16* dst = xbf + (size_t)m * E_;
    const int e = threadIdx.x * 4;
    float4 v = *(const float4*)(src + e);
    ushort4 o; o.x = f2bf(v.x); o.y = f2bf(v.y); o.z = f2bf(v.z); o.w = f2bf(v.w);
    *(ushort4*)(dst + e) = o;
}

// pack [Wi | Wh] per logical wg, B-fragment order, XOR-swizzled 16B groups.
// half 0 = Wi (first 64KB of wg slice), half 1 = Wh (second 64KB).
__global__ void k_packw(const float* __restrict__ Wi1, const float* __restrict__ Wh1,
                        const float* __restrict__ Wi2, const float* __restrict__ Wh2,
                        u16* __restrict__ whp) {
    const int gi  = blockIdx.x * 256 + threadIdx.x;    // 0..2,097,151
    const int half = gi >> 20;
    const int r   = gi & 1048575;
    const int wg  = r >> 12;
    const int lin = r & 4095;
    const int kc  = lin & 127;
    const int col = lin >> 7;                          // 0..31
    const int dir = wg >> 7, hblk = wg & 127;
    const int g = col >> 3, hh = col & 7;
    const float* W = half ? (dir ? Wh2 : Wh1) : (dir ? Wi2 : Wi1);
    const float* src = W + (size_t)(g * H_ + hblk * 8 + hh) * H_ + kc * 8;
    float4 v0 = *(const float4*)(src);
    float4 v1 = *(const float4*)(src + 4);
    const uint32_t boff = (uint32_t)(((kc * 32 + col) * 16) ^ ((kc & 3) << 4));
    u16* dst = whp + (size_t)wg * 65536 + half * 32768 + boff / 2;
    ushort4 o0, o1;
    o0.x = f2bf(v0.x); o0.y = f2bf(v0.y); o0.z = f2bf(v0.z); o0.w = f2bf(v0.w);
    o1.x = f2bf(v1.x); o1.y = f2bf(v1.y); o1.z = f2bf(v1.z); o1.w = f2bf(v1.w);
    *(ushort4*)dst = o0;
    *(ushort4*)(dst + 4) = o1;
}

__global__ void k_bias(const float* __restrict__ bi1, const float* __restrict__ bh1,
                       const float* __restrict__ bi2, const float* __restrict__ bh2,
                       float* __restrict__ bsum) {
    const int i = blockIdx.x * 256 + threadIdx.x;     // 0..8191
    bsum[i] = (i < 4096) ? (bi1[i] + bh1[i]) : (bi2[i - 4096] + bh2[i - 4096]);
}

// ---------------- fused persistent recurrent kernel ----------------
// 256 wgs x 512 thr, 1 wg/CU. wg -> (dir = wg>>7, hblk = wg&127): 32 gate-cols.
// Waves: (mtile 0..3, khalf 0..1). Sync/publish = R7 structure (frozen).
// Fused input projection: gates = [x_t | h] @ [Wi|Wh]^T, K=2048, fp32 acc.
// R12 change: x A-frags are prefetched ONE STEP AHEAD (xa(s+1) issued right
// after xa(s) is consumed) so the poll's wait_vm0 never drains fresh xa loads
// — removes ~1us of xbf fetch latency from the critical step cycle.
__global__ __launch_bounds__(512, 1) void k_lstm(
    const u16* __restrict__ xbf, const u16* __restrict__ whp,
    const float* __restrict__ bsum, u16* hrot,
    float* __restrict__ obuf, unsigned* cnt) {
    __shared__ __align__(16) u16 wlds[65536];    // 128 KB: [Wi | Wh] slice
    __shared__ float glds[2][64][35];            // [khalf][row][col] partial gates
    __shared__ __align__(16) u16 hxch[64][8];    // h exchange (contiguous rows)
    const int wg = blockIdx.x;
    const int dir = wg >> 7, hblk = wg & 127;
    const int tid = threadIdx.x;
    const int wid = tid >> 6, lane = tid & 63;
    const int mtile = wid & 3, khalf = wid >> 2;
    const int col16 = lane & 15, kslot = lane >> 4;
    {   // preload [Wi|Wh] slice (swizzle baked in by k_packw): 128 KB
        const u32x4* s = (const u32x4*)(whp + (size_t)wg * 65536);
        u32x4* d = (u32x4*)wlds;
#pragma unroll
        for (int i = 0; i < 16; ++i) d[tid + i * 512] = s[tid + i * 512];
    }
    const int fb = tid >> 3, fh = tid & 7;       // finish-phase (batch, h-sub)
    const int hidx = hblk * 8 + fh;
    const int arow = mtile * 16 + col16;         // batch row for A-frags
    float bsF[4];
#pragma unroll
    for (int g = 0; g < 4; ++g) bsF[g] = bsum[dir * 4096 + g * 1024 + hidx];
    // per-wave poll pointer: this wave's 64 producers, flags padded 128 B apart
    const unsigned* pollp = cnt + (size_t)(dir * 128 + khalf * 64 + lane) * 32;
    unsigned* flag_own = cnt + (size_t)(dir * 128 + hblk) * 32;
    float cc = 0.f;
    bf16x8 xa[16];
    {   // xa prefetch for step 0
        const u16* xrow = xbf + (size_t)((dir ? (T_ - 1) : 0) * 64 + arow) * 1024 + khalf * 512;
#pragma unroll
        for (int kk = 0; kk < 16; ++kk)
            xa[kk] = *(const bf16x8*)(xrow + kk * 32 + kslot * 8);
    }
    __syncthreads();                              // wlds ready
    for (int s = 0; s < T_; ++s) {
        if (s > 0) {                              // EVERY wave polls its own 64 flags
            const unsigned target = (unsigned)s;
            for (;;) {
                unsigned f;
                ldg4_cc(f, pollp);
                wait_vm0();                       // xa(s) prefetched last step: drained long ago
                if (__all(f >= target)) break;
                __builtin_amdgcn_s_sleep(1);
            }
        }
        __builtin_amdgcn_sched_barrier(0);        // pin h loads behind the poll
        // ---- h A-frags (issue; in flight during x-part MFMA) ----
        const u16* hbase = hrot + (size_t)(s * 2 + dir) * 131072
                         + (size_t)(khalf * 64) * 512 + arow * 8;
        bf16x8 hf[16];
#pragma unroll
        for (int kk = 0; kk < 16; ++kk)
            hf[kk] = *(const bf16x8*)(hbase + (size_t)(kk * 4 + kslot) * 512);
        f32x4 acc0 = {0.f, 0.f, 0.f, 0.f}, acc1 = {0.f, 0.f, 0.f, 0.f};
        // ---- x-part: acc += xa @ Wi (first 64KB of wlds) ----
#pragma unroll
        for (int kk = 0; kk < 16; ++kk) {
            const int kc = khalf * 64 + kk * 4 + kslot;
            const uint32_t base = (uint32_t)(kc * 512);
            const uint32_t sw = (uint32_t)((kc & 3) << 4);
            bf16x8 b0 = *(const bf16x8*)((const char*)wlds + ((base + (uint32_t)(col16 * 16)) ^ sw));
            bf16x8 b1 = *(const bf16x8*)((const char*)wlds + ((base + (uint32_t)(256 + col16 * 16)) ^ sw));
            acc0 = __builtin_amdgcn_mfma_f32_16x16x32_bf16(xa[kk], b0, acc0, 0, 0, 0);
            acc1 = __builtin_amdgcn_mfma_f32_16x16x32_bf16(xa[kk], b1, acc1, 0, 0, 0);
        }
        // ---- xa prefetch for step s+1 (latency hides under h-MFMA/finish/poll)
        if (s < T_ - 1) {
            const int tn = dir ? (T_ - 2 - s) : (s + 1);
            const u16* xrown = xbf + (size_t)(tn * 64 + arow) * 1024 + khalf * 512;
#pragma unroll
            for (int kk = 0; kk < 16; ++kk)
                xa[kk] = *(const bf16x8*)(xrown + kk * 32 + kslot * 8);
        }
        // ---- h-part: acc += hf @ Wh (second 64KB of wlds) ----
#pragma unroll
        for (int kk = 0; kk < 16; ++kk) {
            const int kc = khalf * 64 + kk * 4 + kslot;
            const uint32_t base = (uint32_t)(65536 + kc * 512);
            const uint32_t sw = (uint32_t)((kc & 3) << 4);
            bf16x8 b0 = *(const bf16x8*)((const char*)wlds + ((base + (uint32_t)(col16 * 16)) ^ sw));
            bf16x8 b1 = *(const bf16x8*)((const char*)wlds + ((base + (uint32_t)(256 + col16 * 16)) ^ sw));
            acc0 = __builtin_amdgcn_mfma_f32_16x16x32_bf16(hf[kk], b0, acc0, 0, 0, 0);
            acc1 = __builtin_amdgcn_mfma_f32_16x16x32_bf16(hf[kk], b1, acc1, 0, 0, 0);
        }
#pragma unroll
        for (int q = 0; q < 4; ++q) {
            glds[khalf][mtile * 16 + kslot * 4 + q][col16]      = acc0[q];
            glds[khalf][mtile * 16 + kslot * 4 + q][16 + col16] = acc1[q];
        }
        __syncthreads();                          // sync A: gates ready
        // ---- finish: gates -> elementwise -> h into LDS exchange ----
        const float gi = glds[0][fb][fh]      + glds[1][fb][fh]      + bsF[0];
        const float gf = glds[0][fb][8 + fh]  + glds[1][fb][8 + fh]  + bsF[1];
        const float gc = glds[0][fb][16 + fh] + glds[1][fb][16 + fh] + bsF[2];
        const float go = glds[0][fb][24 + fh] + glds[1][fb][24 + fh] + bsF[3];
        const float iv = sigm(gi), fv = sigm(gf), gv = tanh_f(gc), ov = sigm(go);
        cc = fv * cc + iv * gv;
        const float hv = ov * tanh_f(cc);
        hxch[fb][fh] = f2bf(hv);
        if (s == T_ - 1) obuf[(size_t)(dir * 64 + fb) * 1024 + hidx] = ov;
        __syncthreads();                          // sync B: hxch ready
        if (wid == 0) {                           // wave0: 1-instr publish + flag
            bf16x8 hv8 = *(const bf16x8*)(&hxch[lane][0]);
            u16* hst = hrot + (size_t)((s + 1) * 2 + dir) * 131072
                     + (size_t)hblk * 512 + lane * 8;
            stg16_cc(hst, hv8);
            wait_vm0();                           // single-instruction ack (xa long done)
            if (lane == 0) stg4_cc(flag_own, (unsigned)(s + 1));
        }
    }
}

// ---------------- epilogue ----------------

__global__ void k_osum(const float* __restrict__ obuf, u16* __restrict__ osum) {
    const int i = blockIdx.x * 256 + threadIdx.x;   // 65536
    osum[i] = f2bf(obuf[i] + obuf[65536 + i]);
}

__global__ __launch_bounds__(256) void k_cls(const u16* __restrict__ osum,
                                             const float* __restrict__ W,
                                             const float* __restrict__ bias,
                                             float* __restrict__ out) {
    const int blk = blockIdx.x;                     // 0..249
    const int tid = threadIdx.x, wid = tid >> 6, lane = tid & 63;
    const int col16 = lane & 15, kslot = lane >> 4;
    const int ncol0 = blk * 128 + wid * 32;
    f32x4 acc[4][2] = {};
    for (int kk = 0; kk < 32; ++kk) {
        const int kof = kk * 32 + kslot * 8;
        bf16x8 a[4];
#pragma unroll
        for (int mi = 0; mi < 4; ++mi)
            a[mi] = *(const bf16x8*)(osum + (mi * 16 + col16) * 1024 + kof);
#pragma unroll
        for (int nt = 0; nt < 2; ++nt) {
            const float* wr = W + (size_t)(ncol0 + nt * 16 + col16) * 1024 + kof;
            float4 w0 = *(const float4*)wr;
            float4 w1 = *(const float4*)(wr + 4);
            union { bf16x8 v; u16 u[8]; } bb;
            bb.u[0] = f2bf(w0.x); bb.u[1] = f2bf(w0.y); bb.u[2] = f2bf(w0.z); bb.u[3] = f2bf(w0.w);
            bb.u[4] = f2bf(w1.x); bb.u[5] = f2bf(w1.y); bb.u[6] = f2bf(w1.z); bb.u[7] = f2bf(w1.w);
#pragma unroll
            for (int mi = 0; mi < 4; ++mi)
                acc[mi][nt] = __builtin_amdgcn_mfma_f32_16x16x32_bf16(a[mi], bb.v, acc[mi][nt], 0, 0, 0);
        }
    }
#pragma unroll
    for (int nt = 0; nt < 2; ++nt) {
        const int cn = ncol0 + nt * 16 + col16;
        const float bv = bias[cn];
#pragma unroll
        for (int mi = 0; mi < 4; ++mi)
#pragma unroll
            for (int q = 0; q < 4; ++q)
                out[(size_t)(mi * 16 + kslot * 4 + q) * CLS + cn] = acc[mi][nt][q] + bv;
    }
}

// ---------------- launcher ----------------

extern "C" void kernel_launch(void* const* d_in, const int* in_sizes, int n_in,
                              void* d_out, int out_size, void* d_ws, size_t ws_size,
                              hipStream_t stream) {
    const int*   X   = (const int*)d_in[0];
    const float* emb = (const float*)d_in[1];
    const float* Wi1 = (const float*)d_in[2];
    const float* Wh1 = (const float*)d_in[3];
    const float* bi1 = (const float*)d_in[4];
    const float* bh1 = (const float*)d_in[5];
    const float* Wi2 = (const float*)d_in[6];
    const float* Wh2 = (const float*)d_in[7];
    const float* bi2 = (const float*)d_in[8];
    const float* bh2 = (const float*)d_in[9];
    const float* W   = (const float*)d_in[10];
    const float* bb  = (const float*)d_in[11];
    float* out = (float*)d_out;
    char* ws = (char*)d_ws;

    u16*      xbf   = (u16*)(ws + OFF_XBF);
    u16*      whp   = (u16*)(ws + OFF_WHP);
    unsigned* cnt   = (unsigned*)(ws + OFF_FLG);
    float*    bsum  = (float*)(ws + OFF_BSUM);
    float*    obuf  = (float*)(ws + OFF_OBUF);
    u16*      osum  = (u16*)(ws + OFF_OSUM);
    u16*      hrot  = (u16*)(ws + OFF_HROT);

    k_gather<<<dim3(16384), dim3(256), 0, stream>>>(X, emb, xbf);
    k_packw<<<dim3(8192), dim3(256), 0, stream>>>(Wi1, Wh1, Wi2, Wh2, whp);
    k_bias<<<dim3(32), dim3(256), 0, stream>>>(bi1, bh1, bi2, bh2, bsum);
    hipMemsetAsync(hrot, 0, 262144, stream);       // h_0 = 0 for BOTH dirs
    hipMemsetAsync(cnt, 0, 32768, stream);         // step flags
    {
        const u16* xb_p = xbf; const u16* whp_p = whp; const float* bs_p = bsum;
        u16* hr_p = hrot; float* ob_p = obuf; unsigned* cnt_p = cnt;
        void* args[] = { (void*)&xb_p, (void*)&whp_p, (void*)&bs_p,
                         (void*)&hr_p, (void*)&ob_p, (void*)&cnt_p };
        hipError_t e = hipLaunchCooperativeKernel((void*)k_lstm, dim3(NWG), dim3(512),
                                                  args, 0, stream);
        if (e != hipSuccess) {
            // fallback: 256 wgs at 1 wg/CU are co-resident on a 256-CU chip
            k_lstm<<<dim3(NWG), dim3(512), 0, stream>>>(xbf, whp, bsum, hrot, obuf, cnt);
        }
    }
    k_osum<<<dim3(256), dim3(256), 0, stream>>>(obuf, osum);
    k_cls<<<dim3(250), dim3(256), 0, stream>>>(osum, W, bb, out);
    (void)in_sizes; (void)n_in; (void)out_size; (void)ws_size;
}

// Round 14
// 2135.706 us; speedup vs baseline: 1.0522x; 1.0522x over previous
//
#include <hip/hip_runtime.h>
#include <hip/hip_bf16.h>
#include <stdint.h>

typedef __attribute__((ext_vector_type(4))) float    f32x4;
typedef __attribute__((ext_vector_type(8))) short    bf16x8;
typedef __attribute__((ext_vector_type(4))) uint32_t u32x4;
typedef unsigned short u16;

#define T_   256
#define B_   64
#define E_   1024
#define H_   1024
#define CLS  32000
#define NWG  256

// workspace layout (bytes)
#define OFF_XBF   0ull            // [16384][1024] bf16       33,554,432 (LIVE through k_lstm)
#define OFF_WHP   33554432ull     // [256 wg][Wi 64KB | Wh 64KB] 33,554,432
#define OFF_FLG   67108864ull     // [2*128] flags, 128B apart    32,768
#define OFF_BSUM  67141632ull     // [2][4096] f32                32,768
#define OFF_OBUF  67174400ull     // [2 dir][64][1024] f32       524,288
#define OFF_OSUM  67698688ull     // [64][1024] bf16             131,072
#define OFF_HROT  67829760ull     // rotating h: slot (s,dir) = (s*2+dir)*131072 B; 67,371,008

__device__ __forceinline__ u16 f2bf(float f) {
    union { float f; uint32_t i; } v; v.f = f;
    uint32_t r = v.i + 0x7fffu + ((v.i >> 16) & 1u);
    return (u16)(r >> 16);
}
__device__ __forceinline__ float sigm(float x)   { return 1.f / (1.f + __expf(-x)); }
__device__ __forceinline__ float tanh_f(float x) { return 1.f - 2.f / (__expf(2.f * x) + 1.f); }

// agent-coherent (MALL) accesses — bypass L1/L2, no cache-wide ops anywhere
__device__ __forceinline__ void ldg4_cc(unsigned& d, const unsigned* p) {
    asm volatile("global_load_dword %0, %1, off sc0 sc1"
                 : "=v"(d) : "v"(p) : "memory");
}
__device__ __forceinline__ void stg16_cc(u16* p, bf16x8 v) {
    asm volatile("global_store_dwordx4 %0, %1, off sc0 sc1"
                 :: "v"(p), "v"(v) : "memory");
}
__device__ __forceinline__ void stg4_cc(unsigned* p, unsigned v) {
    asm volatile("global_store_dword %0, %1, off sc0 sc1"
                 :: "v"(p), "v"(v) : "memory");
}
__device__ __forceinline__ void wait_vm0() {
    asm volatile("s_waitcnt vmcnt(0)" ::: "memory");
}

// ---------------- prep kernels ----------------

__global__ void k_gather(const int* __restrict__ X, const float* __restrict__ emb,
                         u16* __restrict__ xbf) {
    const int m = blockIdx.x;            // t*64+b
    const int t = m >> 6, b = m & 63;
    const int tok = X[b * T_ + t];
    const float* src = emb + (size_t)tok * E_;
    u16* dst = xbf + (size_t)m * E_;
    const int e = threadIdx.x * 4;
    float4 v = *(const float4*)(src + e);
    ushort4 o; o.x = f2bf(v.x); o.y = f2bf(v.y); o.z = f2bf(v.z); o.w = f2bf(v.w);
    *(ushort4*)(dst + e) = o;
}

// pack [Wi | Wh] per logical wg, B-fragment order, XOR-swizzled 16B groups.
// half 0 = Wi (first 64KB of wg slice), half 1 = Wh (second 64KB).
__global__ void k_packw(const float* __restrict__ Wi1, const float* __restrict__ Wh1,
                        const float* __restrict__ Wi2, const float* __restrict__ Wh2,
                        u16* __restrict__ whp) {
    const int gi  = blockIdx.x * 256 + threadIdx.x;    // 0..2,097,151
    const int half = gi >> 20;
    const int r   = gi & 1048575;
    const int wg  = r >> 12;
    const int lin = r & 4095;
    const int kc  = lin & 127;
    const int col = lin >> 7;                          // 0..31
    const int dir = wg >> 7, hblk = wg & 127;
    const int g = col >> 3, hh = col & 7;
    const float* W = half ? (dir ? Wh2 : Wh1) : (dir ? Wi2 : Wi1);
    const float* src = W + (size_t)(g * H_ + hblk * 8 + hh) * H_ + kc * 8;
    float4 v0 = *(const float4*)(src);
    float4 v1 = *(const float4*)(src + 4);
    const uint32_t boff = (uint32_t)(((kc * 32 + col) * 16) ^ ((kc & 3) << 4));
    u16* dst = whp + (size_t)wg * 65536 + half * 32768 + boff / 2;
    ushort4 o0, o1;
    o0.x = f2bf(v0.x); o0.y = f2bf(v0.y); o0.z = f2bf(v0.z); o0.w = f2bf(v0.w);
    o1.x = f2bf(v1.x); o1.y = f2bf(v1.y); o1.z = f2bf(v1.z); o1.w = f2bf(v1.w);
    *(ushort4*)dst = o0;
    *(ushort4*)(dst + 4) = o1;
}

__global__ void k_bias(const float* __restrict__ bi1, const float* __restrict__ bh1,
                       const float* __restrict__ bi2, const float* __restrict__ bh2,
                       float* __restrict__ bsum) {
    const int i = blockIdx.x * 256 + threadIdx.x;     // 0..8191
    bsum[i] = (i < 4096) ? (bi1[i] + bh1[i]) : (bi2[i - 4096] + bh2[i - 4096]);
}

// ---------------- fused persistent recurrent kernel (role-split waves) -------
// 256 wgs x 512 thr, 1 wg/CU. wg -> (dir = wg>>7, hblk = wg&127): 32 gate-cols.
// ROLE SPLIT: waves 0-3 ("x") compute x_t @ Wi over full K=1024 for mtile
// (wid&3) — NO poll, NO publish, no sync-coupled waitcnt: their xbf load
// latency hides under the h-waves' poll. Waves 4-7 ("h") poll all 128 own-dir
// flags (2/lane), load h, compute h @ Wh over K=1024. Wave 4 publishes the
// wg's 1KB h slice (single dwordx4 fan, sc0 sc1) + ack + padded flag — its
// only outstanding VM ops are long-drained h-frags, so the ack is clean.
// glds[0] (x-partial) + glds[1] (h-partial) are summed in the finish phase.
// Sync/publish structure otherwise = R7/R10 (best measured, frozen).
__global__ __launch_bounds__(512, 1) void k_lstm(
    const u16* __restrict__ xbf, const u16* __restrict__ whp,
    const float* __restrict__ bsum, u16* hrot,
    float* __restrict__ obuf, unsigned* cnt) {
    __shared__ __align__(16) u16 wlds[65536];    // 128 KB: [Wi | Wh] slice
    __shared__ float glds[2][64][35];            // [part][row][col] partial gates
    __shared__ __align__(16) u16 hxch[64][8];    // h exchange (contiguous rows)
    const int wg = blockIdx.x;
    const int dir = wg >> 7, hblk = wg & 127;
    const int tid = threadIdx.x;
    const int wid = tid >> 6, lane = tid & 63;
    const int mtile = wid & 3, part = wid >> 2;  // part 0 = x, 1 = h
    const int col16 = lane & 15, kslot = lane >> 4;
    {   // preload [Wi|Wh] slice (swizzle baked in by k_packw): 128 KB
        const u32x4* s = (const u32x4*)(whp + (size_t)wg * 65536);
        u32x4* d = (u32x4*)wlds;
#pragma unroll
        for (int i = 0; i < 16; ++i) d[tid + i * 512] = s[tid + i * 512];
    }
    const int fb = tid >> 3, fh = tid & 7;       // finish-phase (batch, h-sub)
    const int hidx = hblk * 8 + fh;
    const int arow = mtile * 16 + col16;         // batch row for A-frags
    float bsF[4];
#pragma unroll
    for (int g = 0; g < 4; ++g) bsF[g] = bsum[dir * 4096 + g * 1024 + hidx];
    // h-wave poll pointers: all 128 own-dir producers, 2 flags per lane
    const unsigned* poll0 = cnt + (size_t)(dir * 128 + lane) * 32;
    const unsigned* poll1 = cnt + (size_t)(dir * 128 + 64 + lane) * 32;
    unsigned* flag_own = cnt + (size_t)(dir * 128 + hblk) * 32;
    float cc = 0.f;
    __syncthreads();                              // wlds ready
    for (int s = 0; s < T_; ++s) {
        f32x4 acc0 = {0.f, 0.f, 0.f, 0.f}, acc1 = {0.f, 0.f, 0.f, 0.f};
        if (part == 0) {
            // ---- x-waves: free-running x_t @ Wi, K=1024 ----
            const int t = dir ? (T_ - 1 - s) : s;
            const u16* xrow = xbf + (size_t)(t * 64 + arow) * 1024;
#pragma unroll
            for (int kk = 0; kk < 32; ++kk) {
                bf16x8 a = *(const bf16x8*)(xrow + kk * 32 + kslot * 8);
                const int kc = kk * 4 + kslot;
                const uint32_t base = (uint32_t)(kc * 512);
                const uint32_t sw = (uint32_t)((kc & 3) << 4);
                bf16x8 b0 = *(const bf16x8*)((const char*)wlds + ((base + (uint32_t)(col16 * 16)) ^ sw));
                bf16x8 b1 = *(const bf16x8*)((const char*)wlds + ((base + (uint32_t)(256 + col16 * 16)) ^ sw));
                acc0 = __builtin_amdgcn_mfma_f32_16x16x32_bf16(a, b0, acc0, 0, 0, 0);
                acc1 = __builtin_amdgcn_mfma_f32_16x16x32_bf16(a, b1, acc1, 0, 0, 0);
            }
#pragma unroll
            for (int q = 0; q < 4; ++q) {
                glds[0][mtile * 16 + kslot * 4 + q][col16]      = acc0[q];
                glds[0][mtile * 16 + kslot * 4 + q][16 + col16] = acc1[q];
            }
        } else {
            // ---- h-waves: poll -> load h -> h @ Wh, K=1024 ----
            if (s > 0) {
                const unsigned target = (unsigned)s;
                for (;;) {
                    unsigned f0, f1;
                    ldg4_cc(f0, poll0);
                    ldg4_cc(f1, poll1);
                    wait_vm0();
                    if (__all(f0 >= target && f1 >= target)) break;
                    __builtin_amdgcn_s_sleep(1);
                }
            }
            __builtin_amdgcn_sched_barrier(0);    // pin h loads behind the poll
            const u16* hbase = hrot + (size_t)(s * 2 + dir) * 131072;
            bf16x8 hf[16];
#pragma unroll
            for (int half = 0; half < 2; ++half) {
#pragma unroll
                for (int kk = 0; kk < 16; ++kk) {
                    const int kc = (half * 16 + kk) * 4 + kslot;
                    hf[kk] = *(const bf16x8*)(hbase + (size_t)kc * 512 + arow * 8);
                }
#pragma unroll
                for (int kk = 0; kk < 16; ++kk) {
                    const int kc = (half * 16 + kk) * 4 + kslot;
                    const uint32_t base = (uint32_t)(65536 + kc * 512);
                    const uint32_t sw = (uint32_t)((kc & 3) << 4);
                    bf16x8 b0 = *(const bf16x8*)((const char*)wlds + ((base + (uint32_t)(col16 * 16)) ^ sw));
                    bf16x8 b1 = *(const bf16x8*)((const char*)wlds + ((base + (uint32_t)(256 + col16 * 16)) ^ sw));
                    acc0 = __builtin_amdgcn_mfma_f32_16x16x32_bf16(hf[kk], b0, acc0, 0, 0, 0);
                    acc1 = __builtin_amdgcn_mfma_f32_16x16x32_bf16(hf[kk], b1, acc1, 0, 0, 0);
                }
            }
#pragma unroll
            for (int q = 0; q < 4; ++q) {
                glds[1][mtile * 16 + kslot * 4 + q][col16]      = acc0[q];
                glds[1][mtile * 16 + kslot * 4 + q][16 + col16] = acc1[q];
            }
        }
        __syncthreads();                          // sync A: both partials ready
        // ---- finish: gates -> elementwise -> h into LDS exchange ----
        const float gi = glds[0][fb][fh]      + glds[1][fb][fh]      + bsF[0];
        const float gf = glds[0][fb][8 + fh]  + glds[1][fb][8 + fh]  + bsF[1];
        const float gc = glds[0][fb][16 + fh] + glds[1][fb][16 + fh] + bsF[2];
        const float go = glds[0][fb][24 + fh] + glds[1][fb][24 + fh] + bsF[3];
        const float iv = sigm(gi), fv = sigm(gf), gv = tanh_f(gc), ov = sigm(go);
        cc = fv * cc + iv * gv;
        const float hv = ov * tanh_f(cc);
        hxch[fb][fh] = f2bf(hv);
        if (s == T_ - 1) obuf[(size_t)(dir * 64 + fb) * 1024 + hidx] = ov;
        __syncthreads();                          // sync B: hxch ready, glds drained
        if (wid == 4) {                           // wave4 (h-group): publish + flag
            bf16x8 hv8 = *(const bf16x8*)(&hxch[lane][0]);
            u16* hst = hrot + (size_t)((s + 1) * 2 + dir) * 131072
                     + (size_t)hblk * 512 + lane * 8;
            stg16_cc(hst, hv8);
            wait_vm0();                           // drains only h-frags (done) + store
            if (lane == 0) stg4_cc(flag_own, (unsigned)(s + 1));
        }
    }
}

// ---------------- epilogue ----------------

__global__ void k_osum(const float* __restrict__ obuf, u16* __restrict__ osum) {
    const int i = blockIdx.x * 256 + threadIdx.x;   // 65536
    osum[i] = f2bf(obuf[i] + obuf[65536 + i]);
}

__global__ __launch_bounds__(256) void k_cls(const u16* __restrict__ osum,
                                             const float* __restrict__ W,
                                             const float* __restrict__ bias,
                                             float* __restrict__ out) {
    const int blk = blockIdx.x;                     // 0..249
    const int tid = threadIdx.x, wid = tid >> 6, lane = tid & 63;
    const int col16 = lane & 15, kslot = lane >> 4;
    const int ncol0 = blk * 128 + wid * 32;
    f32x4 acc[4][2] = {};
    for (int kk = 0; kk < 32; ++kk) {
        const int kof = kk * 32 + kslot * 8;
        bf16x8 a[4];
#pragma unroll
        for (int mi = 0; mi < 4; ++mi)
            a[mi] = *(const bf16x8*)(osum + (mi * 16 + col16) * 1024 + kof);
#pragma unroll
        for (int nt = 0; nt < 2; ++nt) {
            const float* wr = W + (size_t)(ncol0 + nt * 16 + col16) * 1024 + kof;
            float4 w0 = *(const float4*)wr;
            float4 w1 = *(const float4*)(wr + 4);
            union { bf16x8 v; u16 u[8]; } bb;
            bb.u[0] = f2bf(w0.x); bb.u[1] = f2bf(w0.y); bb.u[2] = f2bf(w0.z); bb.u[3] = f2bf(w0.w);
            bb.u[4] = f2bf(w1.x); bb.u[5] = f2bf(w1.y); bb.u[6] = f2bf(w1.z); bb.u[7] = f2bf(w1.w);
#pragma unroll
            for (int mi = 0; mi < 4; ++mi)
                acc[mi][nt] = __builtin_amdgcn_mfma_f32_16x16x32_bf16(a[mi], bb.v, acc[mi][nt], 0, 0, 0);
        }
    }
#pragma unroll
    for (int nt = 0; nt < 2; ++nt) {
        const int cn = ncol0 + nt * 16 + col16;
        const float bv = bias[cn];
#pragma unroll
        for (int mi = 0; mi < 4; ++mi)
#pragma unroll
            for (int q = 0; q < 4; ++q)
                out[(size_t)(mi * 16 + kslot * 4 + q) * CLS + cn] = acc[mi][nt][q] + bv;
    }
}

// ---------------- launcher ----------------

extern "C" void kernel_launch(void* const* d_in, const int* in_sizes, int n_in,
                              void* d_out, int out_size, void* d_ws, size_t ws_size,
                              hipStream_t stream) {
    const int*   X   = (const int*)d_in[0];
    const float* emb = (const float*)d_in[1];
    const float* Wi1 = (const float*)d_in[2];
    const float* Wh1 = (const float*)d_in[3];
    const float* bi1 = (const float*)d_in[4];
    const float* bh1 = (const float*)d_in[5];
    const float* Wi2 = (const float*)d_in[6];
    const float* Wh2 = (const float*)d_in[7];
    const float* bi2 = (const float*)d_in[8];
    const float* bh2 = (const float*)d_in[9];
    const float* W   = (const float*)d_in[10];
    const float* bb  = (const float*)d_in[11];
    float* out = (float*)d_out;
    char* ws = (char*)d_ws;

    u16*      xbf   = (u16*)(ws + OFF_XBF);
    u16*      whp   = (u16*)(ws + OFF_WHP);
    unsigned* cnt   = (unsigned*)(ws + OFF_FLG);
    float*    bsum  = (float*)(ws + OFF_BSUM);
    float*    obuf  = (float*)(ws + OFF_OBUF);
    u16*      osum  = (u16*)(ws + OFF_OSUM);
    u16*      hrot  = (u16*)(ws + OFF_HROT);

    k_gather<<<dim3(16384), dim3(256), 0, stream>>>(X, emb, xbf);
    k_packw<<<dim3(8192), dim3(256), 0, stream>>>(Wi1, Wh1, Wi2, Wh2, whp);
    k_bias<<<dim3(32), dim3(256), 0, stream>>>(bi1, bh1, bi2, bh2, bsum);
    hipMemsetAsync(hrot, 0, 262144, stream);       // h_0 = 0 for BOTH dirs
    hipMemsetAsync(cnt, 0, 32768, stream);         // step flags
    {
        const u16* xb_p = xbf; const u16* whp_p = whp; const float* bs_p = bsum;
        u16* hr_p = hrot; float* ob_p = obuf; unsigned* cnt_p = cnt;
        void* args[] = { (void*)&xb_p, (void*)&whp_p, (void*)&bs_p,
                         (void*)&hr_p, (void*)&ob_p, (void*)&cnt_p };
        hipError_t e = hipLaunchCooperativeKernel((void*)k_lstm, dim3(NWG), dim3(512),
                                                  args, 0, stream);
        if (e != hipSuccess) {
            // fallback: 256 wgs at 1 wg/CU are co-resident on a 256-CU chip
            k_lstm<<<dim3(NWG), dim3(512), 0, stream>>>(xbf, whp, bsum, hrot, obuf, cnt);
        }
    }
    k_osum<<<dim3(256), dim3(256), 0, stream>>>(obuf, osum);
    k_cls<<<dim3(250), dim3(256), 0, stream>>>(osum, W, bb, out);
    (void)in_sizes; (void)n_in; (void)out_size; (void)ws_size;
}